// Round 1
// baseline (273.146 us; speedup 1.0000x reference)
//
#include <hip/hip_runtime.h>

#define N_NODES 2048
#define IN_DIM 128
#define HID 64
#define N_EDGES 32768
#define EPS 1e-5f

__device__ __forceinline__ float relu_f(float x) { return fmaxf(x, 0.f); }

// ---------------- LayerNorm of `local` rows (per node, reused by edges) ----------------
__global__ __launch_bounds__(256) void ln_kernel(
    const float* __restrict__ local, const float* __restrict__ ln_w,
    const float* __restrict__ ln_b, float* __restrict__ out)
{
  int wave = threadIdx.x >> 6;
  int lane = threadIdx.x & 63;
  int row = blockIdx.x * 4 + wave;
  const float* x = local + (size_t)row * IN_DIM;
  float x0 = x[lane], x1 = x[lane + 64];
  float s1 = x0 + x1;
  float s2 = x0 * x0 + x1 * x1;
  #pragma unroll
  for (int off = 32; off > 0; off >>= 1) {
    s1 += __shfl_xor(s1, off);
    s2 += __shfl_xor(s2, off);
  }
  float mean = s1 * (1.f / IN_DIM);
  float var = s2 * (1.f / IN_DIM) - mean * mean;  // population var (jnp.var ddof=0)
  float rstd = rsqrtf(var + EPS);
  float* o = out + (size_t)row * IN_DIM;
  o[lane]      = (x0 - mean) * rstd * ln_w[lane] + ln_b[lane];
  o[lane + 64] = (x1 - mean) * rstd * ln_w[lane + 64] + ln_b[lane + 64];
}

// ---------------- p2 = relu(h @ Wp2 + bp2)  [2048, 64] ----------------
__global__ __launch_bounds__(64) void p2_kernel(
    const float* __restrict__ h, const float* __restrict__ Wp2,
    const float* __restrict__ bp2, float* __restrict__ p2)
{
  __shared__ float hs[IN_DIM];
  const int i = blockIdx.x;
  const int j = threadIdx.x;
  hs[j] = h[(size_t)i * IN_DIM + j];
  hs[j + 64] = h[(size_t)i * IN_DIM + 64 + j];
  __syncthreads();
  float acc = bp2[j];
  #pragma unroll 8
  for (int m = 0; m < IN_DIM; ++m) acc += hs[m] * Wp2[m * HID + j];
  p2[(size_t)i * HID + j] = relu_f(acc);
}

// ---------------- p1 = relu(h @ W1 + b1)  [2048, 4096] f32 GEMM ----------------
// 128x128 tile, BK=32, 256 threads, 8x8 microtile split into 2x2 quadrants so
// every LDS fragment read is <=2 lanes/bank (free on gfx950 per m136).
__global__ __launch_bounds__(256) void p1_gemm(
    const float* __restrict__ A,   // h [2048,128]
    const float* __restrict__ B,   // W1 [128,4096]
    const float* __restrict__ bias,
    float* __restrict__ C)
{
  __shared__ float As[32][132];   // [k][m], padded: row stride 132*4B (16B aligned)
  __shared__ float Bs[32][128];
  const int t = threadIdx.x;
  const int bm = (blockIdx.x & 15) * 128;
  const int bn = (blockIdx.x >> 4) * 128;
  const int tx = t & 15;
  const int ty = t >> 4;
  float acc[8][8];
  #pragma unroll
  for (int i = 0; i < 8; ++i)
    #pragma unroll
    for (int j = 0; j < 8; ++j) acc[i][j] = 0.f;

  for (int k0 = 0; k0 < 128; k0 += 32) {
    #pragma unroll
    for (int r = 0; r < 4; ++r) {        // A: 128 rows x 32 k, transposed into LDS
      int idx = t + r * 256;
      int row = idx >> 3;
      int kq = (idx & 7) << 2;
      float4 av = *(const float4*)&A[(size_t)(bm + row) * 128 + k0 + kq];
      As[kq + 0][row] = av.x;
      As[kq + 1][row] = av.y;
      As[kq + 2][row] = av.z;
      As[kq + 3][row] = av.w;
    }
    #pragma unroll
    for (int r = 0; r < 4; ++r) {        // B: 32 k x 128 n
      int idx = t + r * 256;
      int kk = idx >> 5;
      int nq = (idx & 31) << 2;
      *(float4*)&Bs[kk][nq] = *(const float4*)&B[(size_t)(k0 + kk) * 4096 + bn + nq];
    }
    __syncthreads();
    #pragma unroll
    for (int kk = 0; kk < 32; ++kk) {
      float4 a0 = *(const float4*)&As[kk][ty * 4];
      float4 a1 = *(const float4*)&As[kk][64 + ty * 4];
      float4 b0 = *(const float4*)&Bs[kk][tx * 4];
      float4 b1 = *(const float4*)&Bs[kk][64 + tx * 4];
      float ar[8] = {a0.x, a0.y, a0.z, a0.w, a1.x, a1.y, a1.z, a1.w};
      float br[8] = {b0.x, b0.y, b0.z, b0.w, b1.x, b1.y, b1.z, b1.w};
      #pragma unroll
      for (int i = 0; i < 8; ++i)
        #pragma unroll
        for (int j = 0; j < 8; ++j)
          acc[i][j] += ar[i] * br[j];
    }
    __syncthreads();
  }
  #pragma unroll
  for (int i = 0; i < 8; ++i) {
    int row = bm + (i >> 2) * 64 + ty * 4 + (i & 3);
    #pragma unroll
    for (int jh = 0; jh < 2; ++jh) {
      int col = bn + jh * 64 + tx * 4;
      float4 bv = *(const float4*)&bias[col];
      float4 o;
      o.x = relu_f(acc[i][jh * 4 + 0] + bv.x);
      o.y = relu_f(acc[i][jh * 4 + 1] + bv.y);
      o.z = relu_f(acc[i][jh * 4 + 2] + bv.z);
      o.w = relu_f(acc[i][jh * 4 + 3] + bv.w);
      *(float4*)&C[(size_t)row * 4096 + col] = o;
    }
  }
}

// ---------------- per-edge fused kernel ----------------
// g[d] = sum_k p1[src,d,k]*p2[dst,k]  (bng fused into gbuf write)
// out  = relu(bnL(relu(conv)@W2+b2)) + relu(bnG(bng(g)@W3+b3)) + e
__global__ __launch_bounds__(256) void edge_kernel(
    const float* __restrict__ p1, const float* __restrict__ p2,
    const float* __restrict__ lnl,
    const int* __restrict__ src, const int* __restrict__ dst,
    const float* __restrict__ conv_w, const float* __restrict__ conv_b,
    const float* __restrict__ W2, const float* __restrict__ b2,
    const float* __restrict__ W3, const float* __restrict__ b3,
    const float* __restrict__ bng_g, const float* __restrict__ bng_b,
    const float* __restrict__ bnG_g, const float* __restrict__ bnG_b,
    const float* __restrict__ bnL_g, const float* __restrict__ bnL_b,
    const float* __restrict__ e_in, float* __restrict__ out)
{
  __shared__ float p2v[HID];
  __shared__ float gbuf[HID];
  __shared__ float rc[IN_DIM];
  __shared__ float ln0[IN_DIM];
  __shared__ float ln1[IN_DIM];
  __shared__ float gout[HID];
  __shared__ float lout[HID];

  const int e = blockIdx.x;
  const int t = threadIdx.x;
  const int s = src[e];
  const int d = dst[e];
  const float rs = rsqrtf(1.f + EPS);   // eval-mode BN: running_var = 1

  if (t < 128) ln0[t] = lnl[(size_t)s * IN_DIM + t];
  else         ln1[t - 128] = lnl[(size_t)d * IN_DIM + (t - 128)];
  if (t < 64)  p2v[t] = p2[(size_t)d * HID + t];
  __syncthreads();

  // ---- global branch: 64x64 matvec against gathered p1 row ----
  {
    int dd = t >> 2, q = t & 3;   // 64 rows x 4-lane quads over k
    const float* prow = p1 + (size_t)s * (HID * HID) + dd * HID + q * 16;
    float acc = 0.f;
    #pragma unroll
    for (int kk = 0; kk < 4; ++kk) {
      float4 a = *(const float4*)(prow + kk * 4);        // coalesced 64B/lane
      float4 b = *(const float4*)&p2v[q * 16 + kk * 4];  // 4 distinct f4, broadcast
      acc += a.x * b.x + a.y * b.y + a.z * b.z + a.w * b.w;
    }
    acc += __shfl_xor(acc, 1);
    acc += __shfl_xor(acc, 2);
    if (q == 0) gbuf[dd] = acc * (bng_g[dd] * rs) + bng_b[dd];  // fuse first BN
  }

  // ---- local branch: Conv1d(2->1, k=3, pad=1) + relu ----
  if (t < IN_DIM) {
    int x = t;
    float cw0 = conv_w[0], cw1 = conv_w[1], cw2 = conv_w[2];
    float cw3 = conv_w[3], cw4 = conv_w[4], cw5 = conv_w[5];
    float am = (x > 0) ? ln0[x - 1] : 0.f;
    float a0 = ln0[x];
    float ap = (x < IN_DIM - 1) ? ln0[x + 1] : 0.f;
    float bm = (x > 0) ? ln1[x - 1] : 0.f;
    float b0 = ln1[x];
    float bp = (x < IN_DIM - 1) ? ln1[x + 1] : 0.f;
    rc[x] = relu_f(cw0 * am + cw1 * a0 + cw2 * ap +
                   cw3 * bm + cw4 * b0 + cw5 * bp + conv_b[0]);
  }
  __syncthreads();

  // ---- two small matvecs in parallel waves ----
  if (t < 64) {
    int j = t;
    float ug = b3[j];
    #pragma unroll 8
    for (int k = 0; k < HID; ++k) ug += gbuf[k] * W3[k * HID + j];  // W3 coalesced, L1-hot
    gout[j] = ug;
  } else if (t < 128) {
    int j = t - 64;
    float ul = b2[j];
    #pragma unroll 8
    for (int x = 0; x < IN_DIM; ++x) ul += rc[x] * W2[x * HID + j]; // W2 coalesced, L1-hot
    lout[j] = ul;
  }
  __syncthreads();

  if (t < 64) {
    int j = t;
    float vg = relu_f(gout[j] * (bnG_g[j] * rs) + bnG_b[j]);
    float vl = relu_f(lout[j] * (bnL_g[j] * rs) + bnL_b[j]);
    out[(size_t)e * HID + j] = vl + vg + e_in[(size_t)e * HID + j];
  }
}

extern "C" void kernel_launch(void* const* d_in, const int* in_sizes, int n_in,
                              void* d_out, int out_size, void* d_ws, size_t ws_size,
                              hipStream_t stream) {
  const float* h      = (const float*)d_in[0];
  const float* local  = (const float*)d_in[1];
  const float* e_in   = (const float*)d_in[2];
  const int*   src    = (const int*)d_in[3];
  const int*   dst    = (const int*)d_in[4];
  const float* ln_w   = (const float*)d_in[5];
  const float* ln_b   = (const float*)d_in[6];
  const float* conv_w = (const float*)d_in[7];
  const float* conv_b = (const float*)d_in[8];
  const float* W1     = (const float*)d_in[9];
  const float* b1     = (const float*)d_in[10];
  const float* Wp2    = (const float*)d_in[11];
  const float* bp2    = (const float*)d_in[12];
  const float* W2     = (const float*)d_in[13];
  const float* b2     = (const float*)d_in[14];
  const float* W3     = (const float*)d_in[15];
  const float* b3     = (const float*)d_in[16];
  const float* bng_g  = (const float*)d_in[17];
  const float* bng_b  = (const float*)d_in[18];
  const float* bnG_g  = (const float*)d_in[19];
  const float* bnG_b  = (const float*)d_in[20];
  const float* bnL_g  = (const float*)d_in[21];
  const float* bnL_b  = (const float*)d_in[22];
  float* out = (float*)d_out;

  // workspace: p1 (33.55 MB) | p2 (0.5 MB) | ln_local (1 MB) = 35.1 MB
  float* p1  = (float*)d_ws;
  float* p2  = p1 + (size_t)N_NODES * HID * HID;
  float* lnl = p2 + (size_t)N_NODES * HID;

  ln_kernel<<<N_NODES / 4, 256, 0, stream>>>(local, ln_w, ln_b, lnl);
  p2_kernel<<<N_NODES, 64, 0, stream>>>(h, Wp2, bp2, p2);
  p1_gemm<<<512, 256, 0, stream>>>(h, W1, b1, p1);
  edge_kernel<<<N_EDGES, 256, 0, stream>>>(p1, p2, lnl, src, dst, conv_w, conv_b,
      W2, b2, W3, b3, bng_g, bng_b, bnG_g, bnG_b, bnL_g, bnL_b, e_in, out);
}

// Round 2
// 248.561 us; speedup vs baseline: 1.0989x; 1.0989x over previous
//
#include <hip/hip_runtime.h>

#define N_NODES 2048
#define IN_DIM 128
#define HID 64
#define N_EDGES 32768
#define EPS 1e-5f

typedef short short8 __attribute__((ext_vector_type(8)));
typedef float f32x4 __attribute__((ext_vector_type(4)));

__device__ __forceinline__ float relu_f(float x) { return fmaxf(x, 0.f); }

__device__ __forceinline__ unsigned short f2bf(float f) {
  unsigned int u = __float_as_uint(f);
  u = (u + 0x7fffu + ((u >> 16) & 1u)) >> 16;   // RNE
  return (unsigned short)u;
}
__device__ __forceinline__ float bf2f(unsigned short h) {
  return __uint_as_float(((unsigned int)h) << 16);
}

// ---------------- LayerNorm of `local` rows (per node) ----------------
__global__ __launch_bounds__(256) void ln_kernel(
    const float* __restrict__ local, const float* __restrict__ ln_w,
    const float* __restrict__ ln_b, float* __restrict__ out)
{
  int wave = threadIdx.x >> 6;
  int lane = threadIdx.x & 63;
  int row = blockIdx.x * 4 + wave;
  const float* x = local + (size_t)row * IN_DIM;
  float x0 = x[lane], x1 = x[lane + 64];
  float s1 = x0 + x1;
  float s2 = x0 * x0 + x1 * x1;
  #pragma unroll
  for (int off = 32; off > 0; off >>= 1) {
    s1 += __shfl_xor(s1, off);
    s2 += __shfl_xor(s2, off);
  }
  float mean = s1 * (1.f / IN_DIM);
  float var = s2 * (1.f / IN_DIM) - mean * mean;
  float rstd = rsqrtf(var + EPS);
  float* o = out + (size_t)row * IN_DIM;
  o[lane]      = (x0 - mean) * rstd * ln_w[lane] + ln_b[lane];
  o[lane + 64] = (x1 - mean) * rstd * ln_w[lane + 64] + ln_b[lane + 64];
}

// ---------------- p2 = relu(h @ Wp2 + bp2) ----------------
__global__ __launch_bounds__(256) void p2_kernel(
    const float* __restrict__ h, const float* __restrict__ Wp2,
    const float* __restrict__ bp2, float* __restrict__ p2)
{
  __shared__ float hs[4][IN_DIM];
  int wv = threadIdx.x >> 6, l = threadIdx.x & 63;
  int i = blockIdx.x * 4 + wv;
  hs[wv][l] = h[(size_t)i * IN_DIM + l];
  hs[wv][l + 64] = h[(size_t)i * IN_DIM + 64 + l];
  float acc = bp2[l];
  #pragma unroll 8
  for (int m = 0; m < IN_DIM; ++m) acc += hs[wv][m] * Wp2[m * HID + l];
  p2[(size_t)i * HID + l] = relu_f(acc);
}

// ---------------- prep: cast h->bf16, transpose W2/W3 (f32) ----------------
__global__ __launch_bounds__(256) void prep_misc(
    const float* __restrict__ h, const float* __restrict__ W2,
    const float* __restrict__ W3, unsigned short* __restrict__ hb,
    float* __restrict__ W2T, float* __restrict__ W3T)
{
  int b = blockIdx.x, t = threadIdx.x;
  if (b < 256) {           // cast h: 2048*128 = 262144 = 256*256*4
    int idx = (b * 256 + t) * 4;
    float4 v = *(const float4*)(h + idx);
    ushort4 o;
    o.x = f2bf(v.x); o.y = f2bf(v.y); o.z = f2bf(v.z); o.w = f2bf(v.w);
    *(ushort4*)(hb + idx) = o;
  } else if (b == 256) {   // W2T[j][x] = W2[x][j]
    for (int i = t; i < IN_DIM * HID; i += 256) {
      int x = i >> 6, j = i & 63;
      W2T[j * IN_DIM + x] = W2[i];
    }
  } else {                 // W3T[j][k] = W3[k][j]
    for (int i = t; i < HID * HID; i += 256) {
      int k = i >> 6, j = i & 63;
      W3T[j * HID + k] = W3[i];
    }
  }
}

// ---------------- transpose+cast W1 [128,4096] f32 -> w1t bf16 [4096,128] ----------------
__global__ __launch_bounds__(256) void tr_w1(
    const float* __restrict__ W1, unsigned short* __restrict__ w1t)
{
  __shared__ float tile[32][33];
  int n0 = blockIdx.x * 32, k0 = blockIdx.y * 32;
  int tx = threadIdx.x & 31, ty = threadIdx.x >> 5;
  #pragma unroll
  for (int r = 0; r < 4; ++r)
    tile[ty + 8 * r][tx] = W1[(size_t)(k0 + ty + 8 * r) * 4096 + n0 + tx];
  __syncthreads();
  #pragma unroll
  for (int r = 0; r < 4; ++r)
    w1t[(size_t)(n0 + ty + 8 * r) * 128 + k0 + tx] = f2bf(tile[tx][ty + 8 * r]);
}

// ---------------- p1 = relu(h @ W1 + b1) via bf16 MFMA, output bf16 ----------------
// 128x128 tile per block, 4 waves, wave = 32(m) x 128(n). Direct-global frags.
__global__ __launch_bounds__(256) void p1_gemm(
    const unsigned short* __restrict__ hb,   // [2048][128] bf16
    const unsigned short* __restrict__ w1t,  // [4096][128] bf16 (= W1^T)
    const float* __restrict__ b1,
    unsigned short* __restrict__ p1b)        // [2048][4096] bf16
{
  int t = threadIdx.x;
  int w = t >> 6, l = t & 63;
  int lr = l & 15, lq = l >> 4;
  int bm = (blockIdx.x & 15) * 128;
  int bn = (blockIdx.x >> 4) * 128;
  int m0 = bm + w * 32;

  f32x4 acc[2][8];
  #pragma unroll
  for (int mi = 0; mi < 2; ++mi)
    #pragma unroll
    for (int ni = 0; ni < 8; ++ni) acc[mi][ni] = (f32x4){0.f, 0.f, 0.f, 0.f};

  #pragma unroll
  for (int k0 = 0; k0 < 128; k0 += 32) {
    short8 a[2], b[8];
    #pragma unroll
    for (int mi = 0; mi < 2; ++mi)
      a[mi] = *(const short8*)(hb + (size_t)(m0 + mi * 16 + lr) * 128 + k0 + lq * 8);
    #pragma unroll
    for (int ni = 0; ni < 8; ++ni)
      b[ni] = *(const short8*)(w1t + (size_t)(bn + ni * 16 + lr) * 128 + k0 + lq * 8);
    #pragma unroll
    for (int mi = 0; mi < 2; ++mi)
      #pragma unroll
      for (int ni = 0; ni < 8; ++ni)
        acc[mi][ni] = __builtin_amdgcn_mfma_f32_16x16x32_bf16(a[mi], b[ni], acc[mi][ni], 0, 0, 0);
  }

  #pragma unroll
  for (int mi = 0; mi < 2; ++mi)
    #pragma unroll
    for (int ni = 0; ni < 8; ++ni) {
      int col = bn + ni * 16 + lr;
      float bias = b1[col];
      #pragma unroll
      for (int r = 0; r < 4; ++r) {
        int row = m0 + mi * 16 + lq * 4 + r;
        p1b[(size_t)row * 4096 + col] = f2bf(relu_f(acc[mi][ni][r] + bias));
      }
    }
}

// ---------------- counting sort of edges by src ----------------
__global__ void hist_kernel(const int* __restrict__ src, int* __restrict__ cnt) {
  int e = blockIdx.x * 256 + threadIdx.x;
  atomicAdd(&cnt[src[e]], 1);
}

__global__ __launch_bounds__(256) void scan_kernel(
    const int* __restrict__ cnt, int* __restrict__ start, int* __restrict__ cursor)
{
  __shared__ int part[256];
  int t = threadIdx.x;
  int local[8];
  int s = 0;
  #pragma unroll
  for (int i = 0; i < 8; ++i) { local[i] = s; s += cnt[t * 8 + i]; }
  part[t] = s;
  __syncthreads();
  for (int off = 1; off < 256; off <<= 1) {
    int v = (t >= off) ? part[t - off] : 0;
    __syncthreads();
    part[t] += v;
    __syncthreads();
  }
  int base = (t == 0) ? 0 : part[t - 1];
  #pragma unroll
  for (int i = 0; i < 8; ++i) {
    int v = base + local[i];
    start[t * 8 + i] = v;
    cursor[t * 8 + i] = v;
  }
  if (t == 255) start[2048] = part[255];
}

__global__ void scatter_kernel(const int* __restrict__ src,
                               int* __restrict__ cursor, int* __restrict__ perm) {
  int e = blockIdx.x * 256 + threadIdx.x;
  int p = atomicAdd(&cursor[src[e]], 1);
  perm[p] = e;
}

// ---------------- grouped global branch ----------------
// One block per src node: stage p1[src] (bf16->f32) + W3T in LDS once; for each
// edge in group: g = p1 @ p2[dst]; g'=bng(g); u = g' @ W3; vg = relu(bnG(u)).
__global__ __launch_bounds__(256) void gather_mm(
    const unsigned short* __restrict__ p1b, const float* __restrict__ p2,
    const int* __restrict__ dst, const int* __restrict__ perm,
    const int* __restrict__ start, const float* __restrict__ W3T,
    const float* __restrict__ b3,
    const float* __restrict__ bng_g, const float* __restrict__ bng_b,
    const float* __restrict__ bnG_g, const float* __restrict__ bnG_b,
    float* __restrict__ gbuf)
{
  __shared__ float p1p[64][68];
  __shared__ float w3t[64][68];
  __shared__ float p2s[4][4][64];
  __shared__ float gs[4][4][64];

  const int i = blockIdx.x;
  const int t = threadIdx.x;
  const int w = t >> 6, l = t & 63;
  const float rs = rsqrtf(1.f + EPS);

  // stage p1[i]: 4096 bf16, each thread 16 elements (two 16B chunks)
  {
    const unsigned short* pr = p1b + (size_t)i * 4096;
    #pragma unroll
    for (int r = 0; r < 2; ++r) {
      int flat = (r * 256 + t) * 8;
      int d = flat >> 6, k = flat & 63;
      ushort4 u0 = *(const ushort4*)(pr + flat);
      ushort4 u1 = *(const ushort4*)(pr + flat + 4);
      float4 f0 = {bf2f(u0.x), bf2f(u0.y), bf2f(u0.z), bf2f(u0.w)};
      float4 f1 = {bf2f(u1.x), bf2f(u1.y), bf2f(u1.z), bf2f(u1.w)};
      *(float4*)&p1p[d][k] = f0;
      *(float4*)&p1p[d][k + 4] = f1;
    }
    #pragma unroll
    for (int r = 0; r < 4; ++r) {
      int flat = (r * 256 + t) * 4;
      int j = flat >> 6, k = flat & 63;
      *(float4*)&w3t[j][k] = *(const float4*)(W3T + flat);
    }
  }
  __syncthreads();

  const int gstart = start[i], gend = start[i + 1];
  const float bnggl = bng_g[l] * rs, bngbl = bng_b[l];
  const float bnGgl = bnG_g[l] * rs, bnGbl = bnG_b[l];
  const float b3l = b3[l];

  for (int b0 = gstart + w * 4; b0 < gend; b0 += 16) {
    int m = gend - b0; if (m > 4) m = 4;
    int eidx[4];
    #pragma unroll
    for (int je = 0; je < 4; ++je) {
      if (je < m) {
        eidx[je] = perm[b0 + je];
        int dn = dst[eidx[je]];
        p2s[w][je][l] = p2[(size_t)dn * HID + l];
      }
    }
    // phase 1: g[d=l] for 4 edges
    float acc0 = 0.f, acc1 = 0.f, acc2 = 0.f, acc3 = 0.f;
    #pragma unroll
    for (int k0 = 0; k0 < 64; k0 += 4) {
      float4 a4 = *(const float4*)&p1p[l][k0];
      float4 q0 = *(const float4*)&p2s[w][0][k0];
      float4 q1 = *(const float4*)&p2s[w][1][k0];
      float4 q2 = *(const float4*)&p2s[w][2][k0];
      float4 q3 = *(const float4*)&p2s[w][3][k0];
      acc0 += a4.x * q0.x + a4.y * q0.y + a4.z * q0.z + a4.w * q0.w;
      acc1 += a4.x * q1.x + a4.y * q1.y + a4.z * q1.z + a4.w * q1.w;
      acc2 += a4.x * q2.x + a4.y * q2.y + a4.z * q2.z + a4.w * q2.w;
      acc3 += a4.x * q3.x + a4.y * q3.y + a4.z * q3.z + a4.w * q3.w;
    }
    gs[w][0][l] = acc0 * bnggl + bngbl;
    gs[w][1][l] = acc1 * bnggl + bngbl;
    gs[w][2][l] = acc2 * bnggl + bngbl;
    gs[w][3][l] = acc3 * bnggl + bngbl;
    // phase 2: u[j=l] = b3 + g' @ W3
    float u0 = b3l, u1 = b3l, u2 = b3l, u3 = b3l;
    #pragma unroll
    for (int k0 = 0; k0 < 64; k0 += 4) {
      float4 wv = *(const float4*)&w3t[l][k0];
      float4 g0 = *(const float4*)&gs[w][0][k0];
      float4 g1 = *(const float4*)&gs[w][1][k0];
      float4 g2 = *(const float4*)&gs[w][2][k0];
      float4 g3 = *(const float4*)&gs[w][3][k0];
      u0 += wv.x * g0.x + wv.y * g0.y + wv.z * g0.z + wv.w * g0.w;
      u1 += wv.x * g1.x + wv.y * g1.y + wv.z * g1.z + wv.w * g1.w;
      u2 += wv.x * g2.x + wv.y * g2.y + wv.z * g2.z + wv.w * g2.w;
      u3 += wv.x * g3.x + wv.y * g3.y + wv.z * g3.z + wv.w * g3.w;
    }
    float uu[4] = {u0, u1, u2, u3};
    #pragma unroll
    for (int je = 0; je < 4; ++je)
      if (je < m)
        gbuf[(size_t)eidx[je] * HID + l] = relu_f(uu[je] * bnGgl + bnGbl);
  }
}

// ---------------- final per-edge kernel: conv + W2 matvec + combine ----------------
// 16 edges per block (4 waves x 4 edges).
__global__ __launch_bounds__(256) void final_kernel(
    const float* __restrict__ lnl, const int* __restrict__ src,
    const int* __restrict__ dst, const float* __restrict__ conv_w,
    const float* __restrict__ conv_b, const float* __restrict__ W2T,
    const float* __restrict__ b2,
    const float* __restrict__ bnL_g, const float* __restrict__ bnL_b,
    const float* __restrict__ gbuf, const float* __restrict__ e_in,
    float* __restrict__ out)
{
  __shared__ float w2ts[64][132];
  __shared__ float lns[32][132];
  __shared__ float rcs[16][132];
  __shared__ int nodebuf[32];

  const int eb = blockIdx.x * 16;
  const int t = threadIdx.x;
  const int w = t >> 6, l = t & 63;
  const float rs = rsqrtf(1.f + EPS);

  if (t < 32) {
    int ei = t >> 1;
    nodebuf[t] = (t & 1) ? dst[eb + ei] : src[eb + ei];
  }
  // stage W2T: 8192 f32
  #pragma unroll
  for (int r = 0; r < 8; ++r) {
    int flat = (r * 256 + t) * 4;
    int j = flat >> 7, x = flat & 127;
    *(float4*)&w2ts[j][x] = *(const float4*)(W2T + flat);
  }
  __syncthreads();
  // stage LN rows: 32 rows x 128
  #pragma unroll
  for (int r = 0; r < 4; ++r) {
    int flat = (r * 256 + t) * 4;
    int rr = flat >> 7, x = flat & 127;
    *(float4*)&lns[rr][x] = *(const float4*)(lnl + (size_t)nodebuf[rr] * IN_DIM + x);
  }
  __syncthreads();
  // conv: 16 edges x 128
  {
    float cw0 = conv_w[0], cw1 = conv_w[1], cw2 = conv_w[2];
    float cw3 = conv_w[3], cw4 = conv_w[4], cw5 = conv_w[5];
    float cb = conv_b[0];
    #pragma unroll
    for (int r = 0; r < 8; ++r) {
      int flat = r * 256 + t;
      int ei = flat >> 7, x = flat & 127;
      const float* a = &lns[2 * ei][0];
      const float* b = &lns[2 * ei + 1][0];
      float am = (x > 0) ? a[x - 1] : 0.f;
      float ap = (x < 127) ? a[x + 1] : 0.f;
      float bm = (x > 0) ? b[x - 1] : 0.f;
      float bp = (x < 127) ? b[x + 1] : 0.f;
      rcs[ei][x] = relu_f(cw0 * am + cw1 * a[x] + cw2 * ap +
                          cw3 * bm + cw4 * b[x] + cw5 * bp + cb);
    }
  }
  __syncthreads();
  // matvec: wave w -> edges eb+4w..+3, lane l = output j
  {
    float b2l = b2[l];
    float acc0 = b2l, acc1 = b2l, acc2 = b2l, acc3 = b2l;
    #pragma unroll
    for (int x0 = 0; x0 < 128; x0 += 4) {
      float4 wv = *(const float4*)&w2ts[l][x0];
      float4 r0 = *(const float4*)&rcs[4 * w + 0][x0];
      float4 r1 = *(const float4*)&rcs[4 * w + 1][x0];
      float4 r2 = *(const float4*)&rcs[4 * w + 2][x0];
      float4 r3 = *(const float4*)&rcs[4 * w + 3][x0];
      acc0 += wv.x * r0.x + wv.y * r0.y + wv.z * r0.z + wv.w * r0.w;
      acc1 += wv.x * r1.x + wv.y * r1.y + wv.z * r1.z + wv.w * r1.w;
      acc2 += wv.x * r2.x + wv.y * r2.y + wv.z * r2.z + wv.w * r2.w;
      acc3 += wv.x * r3.x + wv.y * r3.y + wv.z * r3.z + wv.w * r3.w;
    }
    float bl_g = bnL_g[l] * rs, bl_b = bnL_b[l];
    float accs[4] = {acc0, acc1, acc2, acc3};
    #pragma unroll
    for (int je = 0; je < 4; ++je) {
      int e = eb + 4 * w + je;
      float vl = relu_f(accs[je] * bl_g + bl_b);
      out[(size_t)e * HID + l] = vl + gbuf[(size_t)e * HID + l] + e_in[(size_t)e * HID + l];
    }
  }
}

extern "C" void kernel_launch(void* const* d_in, const int* in_sizes, int n_in,
                              void* d_out, int out_size, void* d_ws, size_t ws_size,
                              hipStream_t stream) {
  const float* h      = (const float*)d_in[0];
  const float* local  = (const float*)d_in[1];
  const float* e_in   = (const float*)d_in[2];
  const int*   src    = (const int*)d_in[3];
  const int*   dst    = (const int*)d_in[4];
  const float* ln_w   = (const float*)d_in[5];
  const float* ln_b   = (const float*)d_in[6];
  const float* conv_w = (const float*)d_in[7];
  const float* conv_b = (const float*)d_in[8];
  const float* W1     = (const float*)d_in[9];
  const float* b1     = (const float*)d_in[10];
  const float* Wp2    = (const float*)d_in[11];
  const float* bp2    = (const float*)d_in[12];
  const float* W2     = (const float*)d_in[13];
  const float* b2     = (const float*)d_in[14];
  const float* W3     = (const float*)d_in[15];
  const float* b3     = (const float*)d_in[16];
  const float* bng_g  = (const float*)d_in[17];
  const float* bng_b  = (const float*)d_in[18];
  const float* bnG_g  = (const float*)d_in[19];
  const float* bnG_b  = (const float*)d_in[20];
  const float* bnL_g  = (const float*)d_in[21];
  const float* bnL_b  = (const float*)d_in[22];
  float* out = (float*)d_out;

  // ---- workspace layout ----
  char* p = (char*)d_ws;
  unsigned short* p1b = (unsigned short*)p; p += (size_t)N_NODES * HID * HID * 2;  // 16.78 MB
  float* p2v = (float*)p;  p += (size_t)N_NODES * HID * 4;                         // 0.52 MB
  float* lnl = (float*)p;  p += (size_t)N_NODES * IN_DIM * 4;                      // 1.05 MB
  float* gbuf = (float*)p; p += (size_t)N_EDGES * HID * 4;                         // 8.39 MB
  unsigned short* hb = (unsigned short*)p;  p += (size_t)N_NODES * IN_DIM * 2;     // 0.52 MB
  unsigned short* w1t = (unsigned short*)p; p += (size_t)4096 * 128 * 2;           // 1.05 MB
  float* W2T = (float*)p;  p += IN_DIM * HID * 4;
  float* W3T = (float*)p;  p += HID * HID * 4;
  int* cnt = (int*)p;      p += N_NODES * 4;
  int* cursor = (int*)p;   p += N_NODES * 4;
  int* startb = (int*)p;   p += (N_NODES + 1) * 4;
  int* perm = (int*)p;     p += (size_t)N_EDGES * 4;

  hipMemsetAsync(cnt, 0, N_NODES * sizeof(int), stream);

  prep_misc<<<258, 256, 0, stream>>>(h, W2, W3, hb, W2T, W3T);
  tr_w1<<<dim3(128, 4), 256, 0, stream>>>(W1, w1t);
  ln_kernel<<<N_NODES / 4, 256, 0, stream>>>(local, ln_w, ln_b, lnl);
  p2_kernel<<<N_NODES / 4, 256, 0, stream>>>(h, Wp2, bp2, p2v);
  p1_gemm<<<512, 256, 0, stream>>>(hb, w1t, b1, p1b);
  hist_kernel<<<N_EDGES / 256, 256, 0, stream>>>(src, cnt);
  scan_kernel<<<1, 256, 0, stream>>>(cnt, startb, cursor);
  scatter_kernel<<<N_EDGES / 256, 256, 0, stream>>>(src, cursor, perm);
  gather_mm<<<N_NODES, 256, 0, stream>>>(p1b, p2v, dst, perm, startb, W3T, b3,
                                         bng_g, bng_b, bnG_g, bnG_b, gbuf);
  final_kernel<<<N_EDGES / 16, 256, 0, stream>>>(lnl, src, dst, conv_w, conv_b,
                                                 W2T, b2, bnL_g, bnL_b, gbuf, e_in, out);
}

// Round 3
// 188.030 us; speedup vs baseline: 1.4527x; 1.3219x over previous
//
#include <hip/hip_runtime.h>

#define N_NODES 2048
#define IN_DIM 128
#define HID 64
#define N_EDGES 32768
#define EPS 1e-5f

typedef short short8 __attribute__((ext_vector_type(8)));
typedef float f32x4 __attribute__((ext_vector_type(4)));

__device__ __forceinline__ float relu_f(float x) { return fmaxf(x, 0.f); }

__device__ __forceinline__ unsigned short f2bf(float f) {
  unsigned int u = __float_as_uint(f);
  u = (u + 0x7fffu + ((u >> 16) & 1u)) >> 16;   // RNE
  return (unsigned short)u;
}
__device__ __forceinline__ float bf2f(unsigned short h) {
  return __uint_as_float(((unsigned int)h) << 16);
}
__device__ __forceinline__ short8 pack8(const float* f) {
  short8 o;
  #pragma unroll
  for (int i = 0; i < 8; ++i) o[i] = (short)f2bf(f[i]);
  return o;
}

// ---------------- LayerNorm of `local` rows (per node) ----------------
__global__ __launch_bounds__(256) void ln_kernel(
    const float* __restrict__ local, const float* __restrict__ ln_w,
    const float* __restrict__ ln_b, float* __restrict__ out)
{
  int wave = threadIdx.x >> 6;
  int lane = threadIdx.x & 63;
  int row = blockIdx.x * 4 + wave;
  const float* x = local + (size_t)row * IN_DIM;
  float x0 = x[lane], x1 = x[lane + 64];
  float s1 = x0 + x1;
  float s2 = x0 * x0 + x1 * x1;
  #pragma unroll
  for (int off = 32; off > 0; off >>= 1) {
    s1 += __shfl_xor(s1, off);
    s2 += __shfl_xor(s2, off);
  }
  float mean = s1 * (1.f / IN_DIM);
  float var = s2 * (1.f / IN_DIM) - mean * mean;
  float rstd = rsqrtf(var + EPS);
  float* o = out + (size_t)row * IN_DIM;
  o[lane]      = (x0 - mean) * rstd * ln_w[lane] + ln_b[lane];
  o[lane + 64] = (x1 - mean) * rstd * ln_w[lane + 64] + ln_b[lane + 64];
}

// ---------------- p2 = relu(h @ Wp2 + bp2), output bf16 ----------------
__global__ __launch_bounds__(256) void p2_kernel(
    const float* __restrict__ h, const float* __restrict__ Wp2,
    const float* __restrict__ bp2, unsigned short* __restrict__ p2b)
{
  __shared__ float hs[4][IN_DIM];
  int wv = threadIdx.x >> 6, l = threadIdx.x & 63;
  int i = blockIdx.x * 4 + wv;
  hs[wv][l] = h[(size_t)i * IN_DIM + l];
  hs[wv][l + 64] = h[(size_t)i * IN_DIM + 64 + l];
  float acc = bp2[l];
  #pragma unroll 8
  for (int m = 0; m < IN_DIM; ++m) acc += hs[wv][m] * Wp2[m * HID + l];
  p2b[(size_t)i * HID + l] = f2bf(relu_f(acc));
}

// ---------------- prep: cast h->bf16, W2^T/W3^T -> bf16 ----------------
__global__ __launch_bounds__(256) void prep_misc(
    const float* __restrict__ h, const float* __restrict__ W2,
    const float* __restrict__ W3, unsigned short* __restrict__ hb,
    unsigned short* __restrict__ w2tb, unsigned short* __restrict__ w3tb)
{
  int b = blockIdx.x, t = threadIdx.x;
  if (b < 256) {           // cast h: 2048*128 = 262144 = 256*256*4
    int idx = (b * 256 + t) * 4;
    float4 v = *(const float4*)(h + idx);
    ushort4 o;
    o.x = f2bf(v.x); o.y = f2bf(v.y); o.z = f2bf(v.z); o.w = f2bf(v.w);
    *(ushort4*)(hb + idx) = o;
  } else if (b == 256) {   // w2tb[j][x] = bf16(W2[x][j])
    for (int i = t; i < IN_DIM * HID; i += 256) {
      int x = i >> 6, j = i & 63;
      w2tb[j * IN_DIM + x] = f2bf(W2[i]);
    }
  } else {                 // w3tb[j][k] = bf16(W3[k][j])
    for (int i = t; i < HID * HID; i += 256) {
      int k = i >> 6, j = i & 63;
      w3tb[j * HID + k] = f2bf(W3[i]);
    }
  }
}

// ---------------- transpose+cast W1 [128,4096] f32 -> w1t bf16 [4096,128] ----------------
__global__ __launch_bounds__(256) void tr_w1(
    const float* __restrict__ W1, unsigned short* __restrict__ w1t)
{
  __shared__ float tile[32][33];
  int n0 = blockIdx.x * 32, k0 = blockIdx.y * 32;
  int tx = threadIdx.x & 31, ty = threadIdx.x >> 5;
  #pragma unroll
  for (int r = 0; r < 4; ++r)
    tile[ty + 8 * r][tx] = W1[(size_t)(k0 + ty + 8 * r) * 4096 + n0 + tx];
  __syncthreads();
  #pragma unroll
  for (int r = 0; r < 4; ++r)
    w1t[(size_t)(n0 + ty + 8 * r) * 128 + k0 + tx] = f2bf(tile[tx][ty + 8 * r]);
}

// ---------------- p1 = relu(h @ W1 + b1) via bf16 MFMA, output bf16 ----------------
__global__ __launch_bounds__(256) void p1_gemm(
    const unsigned short* __restrict__ hb,   // [2048][128] bf16
    const unsigned short* __restrict__ w1t,  // [4096][128] bf16 (= W1^T)
    const float* __restrict__ b1,
    unsigned short* __restrict__ p1b)        // [2048][4096] bf16
{
  int t = threadIdx.x;
  int w = t >> 6, l = t & 63;
  int lr = l & 15, lq = l >> 4;
  int bm = (blockIdx.x & 15) * 128;
  int bn = (blockIdx.x >> 4) * 128;
  int m0 = bm + w * 32;

  f32x4 acc[2][8];
  #pragma unroll
  for (int mi = 0; mi < 2; ++mi)
    #pragma unroll
    for (int ni = 0; ni < 8; ++ni) acc[mi][ni] = (f32x4){0.f, 0.f, 0.f, 0.f};

  #pragma unroll
  for (int k0 = 0; k0 < 128; k0 += 32) {
    short8 a[2], b[8];
    #pragma unroll
    for (int mi = 0; mi < 2; ++mi)
      a[mi] = *(const short8*)(hb + (size_t)(m0 + mi * 16 + lr) * 128 + k0 + lq * 8);
    #pragma unroll
    for (int ni = 0; ni < 8; ++ni)
      b[ni] = *(const short8*)(w1t + (size_t)(bn + ni * 16 + lr) * 128 + k0 + lq * 8);
    #pragma unroll
    for (int mi = 0; mi < 2; ++mi)
      #pragma unroll
      for (int ni = 0; ni < 8; ++ni)
        acc[mi][ni] = __builtin_amdgcn_mfma_f32_16x16x32_bf16(a[mi], b[ni], acc[mi][ni], 0, 0, 0);
  }

  #pragma unroll
  for (int mi = 0; mi < 2; ++mi)
    #pragma unroll
    for (int ni = 0; ni < 8; ++ni) {
      int col = bn + ni * 16 + lr;
      float bias = b1[col];
      #pragma unroll
      for (int r = 0; r < 4; ++r) {
        int row = m0 + mi * 16 + lq * 4 + r;
        p1b[(size_t)row * 4096 + col] = f2bf(relu_f(acc[mi][ni][r] + bias));
      }
    }
}

// ---------------- counting sort of edges by src + padded tile build ----------------
__global__ void hist_kernel(const int* __restrict__ src, int* __restrict__ cnt) {
  int e = blockIdx.x * 256 + threadIdx.x;
  atomicAdd(&cnt[src[e]], 1);
}

__global__ __launch_bounds__(256) void scan_kernel(
    const int* __restrict__ cnt, int* __restrict__ start,
    int* __restrict__ cursor, int* __restrict__ ptile)
{
  __shared__ int part[256];
  __shared__ int part2[256];
  int t = threadIdx.x;
  int loc[8], locT[8];
  int s = 0, s2 = 0;
  #pragma unroll
  for (int i = 0; i < 8; ++i) {
    int c = cnt[t * 8 + i];
    loc[i] = s;  s += c;
    locT[i] = s2; s2 += (c + 15) >> 4;
  }
  part[t] = s; part2[t] = s2;
  __syncthreads();
  for (int off = 1; off < 256; off <<= 1) {
    int v = (t >= off) ? part[t - off] : 0;
    int v2 = (t >= off) ? part2[t - off] : 0;
    __syncthreads();
    part[t] += v; part2[t] += v2;
    __syncthreads();
  }
  int base = (t == 0) ? 0 : part[t - 1];
  int base2 = (t == 0) ? 0 : part2[t - 1];
  #pragma unroll
  for (int i = 0; i < 8; ++i) {
    int v = base + loc[i];
    start[t * 8 + i] = v;
    cursor[t * 8 + i] = v;
    ptile[t * 8 + i] = base2 + locT[i];
  }
  if (t == 255) { start[N_NODES] = part[255]; ptile[N_NODES] = part2[255]; }
}

__global__ void scatter_kernel(const int* __restrict__ src,
                               int* __restrict__ cursor, int* __restrict__ perm) {
  int e = blockIdx.x * 256 + threadIdx.x;
  int p = atomicAdd(&cursor[src[e]], 1);
  perm[p] = e;
}

__global__ void build_tiles(const int* __restrict__ cnt, const int* __restrict__ start,
                            const int* __restrict__ ptile, const int* __restrict__ perm,
                            int* __restrict__ tile_src, int* __restrict__ perm_padded) {
  int i = blockIdx.x * 256 + threadIdx.x;   // node
  int deg = cnt[i], s0 = start[i], t0 = ptile[i];
  int nt = (deg + 15) >> 4;
  for (int k = 0; k < nt; ++k) {
    int tid = t0 + k;
    tile_src[tid] = i;
    for (int j = 0; j < 16; ++j) {
      int pos = k * 16 + j;
      perm_padded[tid * 16 + j] = (pos < deg) ? perm[s0 + pos] : -1;
    }
  }
}

// ---------------- global branch: one wave per 16-edge tile, MFMA ----------------
// g = p2[dst] @ p1[src]^T ; g' = bng(g) ; u = g' @ W3 ; gbuf = relu(bnG(u+b3))
__global__ __launch_bounds__(256) void gather_mfma(
    const unsigned short* __restrict__ p1b, const unsigned short* __restrict__ p2b,
    const int* __restrict__ dst, const int* __restrict__ perm_padded,
    const int* __restrict__ tile_src, const int* __restrict__ ptile,
    const unsigned short* __restrict__ w3tb, const float* __restrict__ b3,
    const float* __restrict__ bng_g, const float* __restrict__ bng_b,
    const float* __restrict__ bnG_g, const float* __restrict__ bnG_b,
    float* __restrict__ gbuf)
{
  __shared__ float gs[4][16][68];   // per-wave transpose buffer
  const int t = threadIdx.x;
  const int w = t >> 6, l = t & 63;
  const int lr = l & 15, lq = l >> 4;
  const int n_tiles = ptile[N_NODES];
  const float rs = rsqrtf(1.f + EPS);

  float bngG[4], bngB[4], bnGG[4], bnGB[4], b3c[4];
  #pragma unroll
  for (int ni = 0; ni < 4; ++ni) {
    int col = ni * 16 + lr;
    bngG[ni] = bng_g[col] * rs; bngB[ni] = bng_b[col];
    bnGG[ni] = bnG_g[col] * rs; bnGB[ni] = bnG_b[col];
    b3c[ni] = b3[col];
  }

  for (int tile = blockIdx.x * 4 + w; tile < n_tiles; tile += gridDim.x * 4) {
    const int srcn = tile_src[tile];
    const int eidx = perm_padded[tile * 16 + lr];
    const int dn = (eidx >= 0) ? dst[eidx] : 0;

    const unsigned short* p2r = p2b + (size_t)dn * HID + lq * 8;
    short8 a0 = *(const short8*)(p2r);
    short8 a1 = *(const short8*)(p2r + 32);

    const unsigned short* pr = p1b + (size_t)srcn * 4096 + lr * 64 + lq * 8;
    f32x4 c[4];
    #pragma unroll
    for (int ni = 0; ni < 4; ++ni) {
      c[ni] = (f32x4){0.f, 0.f, 0.f, 0.f};
      short8 b0 = *(const short8*)(pr + ni * 1024);
      short8 b1 = *(const short8*)(pr + ni * 1024 + 32);
      c[ni] = __builtin_amdgcn_mfma_f32_16x16x32_bf16(a0, b0, c[ni], 0, 0, 0);
      c[ni] = __builtin_amdgcn_mfma_f32_16x16x32_bf16(a1, b1, c[ni], 0, 0, 0);
    }

    // bng + transpose (edge axis: C-row -> A-row) through per-wave LDS
    #pragma unroll
    for (int ni = 0; ni < 4; ++ni)
      #pragma unroll
      for (int r = 0; r < 4; ++r)
        gs[w][lq * 4 + r][ni * 16 + lr] = c[ni][r] * bngG[ni] + bngB[ni];
    asm volatile("s_waitcnt lgkmcnt(0)" ::: "memory");   // wave-internal LDS visibility

    short8 ga0 = pack8(&gs[w][lr][lq * 8]);
    short8 ga1 = pack8(&gs[w][lr][32 + lq * 8]);

    const unsigned short* wr = w3tb + lr * HID + lq * 8;
    f32x4 u[4];
    #pragma unroll
    for (int ni = 0; ni < 4; ++ni) {
      u[ni] = (f32x4){0.f, 0.f, 0.f, 0.f};
      short8 b0 = *(const short8*)(wr + ni * 1024);
      short8 b1 = *(const short8*)(wr + ni * 1024 + 32);
      u[ni] = __builtin_amdgcn_mfma_f32_16x16x32_bf16(ga0, b0, u[ni], 0, 0, 0);
      u[ni] = __builtin_amdgcn_mfma_f32_16x16x32_bf16(ga1, b1, u[ni], 0, 0, 0);
    }

    int er[4];
    #pragma unroll
    for (int r = 0; r < 4; ++r) er[r] = perm_padded[tile * 16 + lq * 4 + r];
    #pragma unroll
    for (int ni = 0; ni < 4; ++ni) {
      int col = ni * 16 + lr;
      #pragma unroll
      for (int r = 0; r < 4; ++r)
        if (er[r] >= 0)
          gbuf[(size_t)er[r] * HID + col] =
              relu_f((u[ni][r] + b3c[ni]) * bnGG[ni] + bnGB[ni]);
    }
  }
}

// ---------------- final: conv + W2 MFMA + combine, 16 edges/block ----------------
__global__ __launch_bounds__(256) void final_kernel(
    const float* __restrict__ lnl, const int* __restrict__ src,
    const int* __restrict__ dst, const float* __restrict__ conv_w,
    const float* __restrict__ conv_b, const unsigned short* __restrict__ w2tb,
    const float* __restrict__ b2,
    const float* __restrict__ bnL_g, const float* __restrict__ bnL_b,
    const float* __restrict__ gbuf, const float* __restrict__ e_in,
    float* __restrict__ out)
{
  __shared__ float lns[32][132];
  __shared__ unsigned short rc[16][136];   // conv output, bf16, pad 8
  __shared__ int nodebuf[32];

  const int eb = blockIdx.x * 16;
  const int t = threadIdx.x;
  const int w = t >> 6, l = t & 63;
  const int lr = l & 15, lq = l >> 4;
  const float rs = rsqrtf(1.f + EPS);

  if (t < 32) nodebuf[t] = (t & 1) ? dst[eb + (t >> 1)] : src[eb + (t >> 1)];
  __syncthreads();
  #pragma unroll
  for (int r = 0; r < 4; ++r) {
    int flat = (r * 256 + t) * 4;
    int rr = flat >> 7, x = flat & 127;
    *(float4*)&lns[rr][x] = *(const float4*)(lnl + (size_t)nodebuf[rr] * IN_DIM + x);
  }
  __syncthreads();
  {
    float cw0 = conv_w[0], cw1 = conv_w[1], cw2 = conv_w[2];
    float cw3 = conv_w[3], cw4 = conv_w[4], cw5 = conv_w[5];
    float cb = conv_b[0];
    #pragma unroll
    for (int r = 0; r < 8; ++r) {
      int flat = r * 256 + t;
      int ei = flat >> 7, x = flat & 127;
      const float* a = &lns[2 * ei][0];
      const float* b = &lns[2 * ei + 1][0];
      float am = (x > 0) ? a[x - 1] : 0.f;
      float ap = (x < 127) ? a[x + 1] : 0.f;
      float bm = (x > 0) ? b[x - 1] : 0.f;
      float bp = (x < 127) ? b[x + 1] : 0.f;
      rc[ei][x] = f2bf(relu_f(cw0 * am + cw1 * a[x] + cw2 * ap +
                              cw3 * bm + cw4 * b[x] + cw5 * bp + cb));
    }
  }
  __syncthreads();
  // MFMA: wave w computes output cols [16w, 16w+16), K=128 over conv output
  f32x4 u = (f32x4){0.f, 0.f, 0.f, 0.f};
  #pragma unroll
  for (int ks = 0; ks < 4; ++ks) {
    short8 a = *(const short8*)&rc[lr][ks * 32 + lq * 8];
    short8 b = *(const short8*)(w2tb + (size_t)(w * 16 + lr) * IN_DIM + ks * 32 + lq * 8);
    u = __builtin_amdgcn_mfma_f32_16x16x32_bf16(a, b, u, 0, 0, 0);
  }
  int col = w * 16 + lr;
  float g = bnL_g[col] * rs, bb = bnL_b[col], b2c = b2[col];
  #pragma unroll
  for (int r = 0; r < 4; ++r) {
    int e = eb + lq * 4 + r;
    float vl = relu_f((u[r] + b2c) * g + bb);
    out[(size_t)e * HID + col] = vl + gbuf[(size_t)e * HID + col] + e_in[(size_t)e * HID + col];
  }
}

extern "C" void kernel_launch(void* const* d_in, const int* in_sizes, int n_in,
                              void* d_out, int out_size, void* d_ws, size_t ws_size,
                              hipStream_t stream) {
  const float* h      = (const float*)d_in[0];
  const float* local  = (const float*)d_in[1];
  const float* e_in   = (const float*)d_in[2];
  const int*   src    = (const int*)d_in[3];
  const int*   dst    = (const int*)d_in[4];
  const float* ln_w   = (const float*)d_in[5];
  const float* ln_b   = (const float*)d_in[6];
  const float* conv_w = (const float*)d_in[7];
  const float* conv_b = (const float*)d_in[8];
  const float* W1     = (const float*)d_in[9];
  const float* b1     = (const float*)d_in[10];
  const float* Wp2    = (const float*)d_in[11];
  const float* bp2    = (const float*)d_in[12];
  const float* W2     = (const float*)d_in[13];
  const float* b2     = (const float*)d_in[14];
  const float* W3     = (const float*)d_in[15];
  const float* b3     = (const float*)d_in[16];
  const float* bng_g  = (const float*)d_in[17];
  const float* bng_b  = (const float*)d_in[18];
  const float* bnG_g  = (const float*)d_in[19];
  const float* bnG_b  = (const float*)d_in[20];
  const float* bnL_g  = (const float*)d_in[21];
  const float* bnL_b  = (const float*)d_in[22];
  float* out = (float*)d_out;

  // ---- workspace layout ----
  char* p = (char*)d_ws;
  unsigned short* p1b = (unsigned short*)p; p += (size_t)N_NODES * HID * HID * 2;  // 16.78 MB
  unsigned short* p2b = (unsigned short*)p; p += (size_t)N_NODES * HID * 2;        // 0.26 MB
  float* lnl  = (float*)p; p += (size_t)N_NODES * IN_DIM * 4;                      // 1.05 MB
  float* gbuf = (float*)p; p += (size_t)N_EDGES * HID * 4;                         // 8.39 MB
  unsigned short* hb   = (unsigned short*)p; p += (size_t)N_NODES * IN_DIM * 2;    // 0.52 MB
  unsigned short* w1t  = (unsigned short*)p; p += (size_t)4096 * 128 * 2;          // 1.05 MB
  unsigned short* w2tb = (unsigned short*)p; p += (size_t)HID * IN_DIM * 2;        // 16 KB
  unsigned short* w3tb = (unsigned short*)p; p += (size_t)HID * HID * 2;           // 8 KB
  int* cnt    = (int*)p; p += N_NODES * 4;
  int* cursor = (int*)p; p += N_NODES * 4;
  int* startb = (int*)p; p += (N_NODES + 1) * 4;
  int* ptile  = (int*)p; p += (N_NODES + 1) * 4;
  int* perm   = (int*)p; p += (size_t)N_EDGES * 4;
  int* tile_src    = (int*)p; p += 4096 * 4;
  int* perm_padded = (int*)p; p += (size_t)4096 * 16 * 4;                          // 256 KB

  hipMemsetAsync(cnt, 0, N_NODES * sizeof(int), stream);

  prep_misc<<<258, 256, 0, stream>>>(h, W2, W3, hb, w2tb, w3tb);
  tr_w1<<<dim3(128, 4), 256, 0, stream>>>(W1, w1t);
  ln_kernel<<<N_NODES / 4, 256, 0, stream>>>(local, ln_w, ln_b, lnl);
  p2_kernel<<<N_NODES / 4, 256, 0, stream>>>(h, Wp2, bp2, p2b);
  p1_gemm<<<512, 256, 0, stream>>>(hb, w1t, b1, p1b);
  hist_kernel<<<N_EDGES / 256, 256, 0, stream>>>(src, cnt);
  scan_kernel<<<1, 256, 0, stream>>>(cnt, startb, cursor, ptile);
  scatter_kernel<<<N_EDGES / 256, 256, 0, stream>>>(src, cursor, perm);
  build_tiles<<<N_NODES / 256, 256, 0, stream>>>(cnt, startb, ptile, perm, tile_src, perm_padded);
  gather_mfma<<<512, 256, 0, stream>>>(p1b, p2b, dst, perm_padded, tile_src, ptile,
                                       w3tb, b3, bng_g, bng_b, bnG_g, bnG_b, gbuf);
  final_kernel<<<N_EDGES / 16, 256, 0, stream>>>(lnl, src, dst, conv_w, conv_b,
                                                 w2tb, b2, bnL_g, bnL_b, gbuf, e_in, out);
}